// Round 1
// baseline (1264.068 us; speedup 1.0000x reference)
//
#include <hip/hip_runtime.h>
#include <math.h>

#define NBATCH 4
#define NHEAD  16
#define SEQ    2048
#define HDIM   64
#define QT     64
#define KT     64

typedef __attribute__((ext_vector_type(4))) float f4;
typedef __attribute__((ext_vector_type(4))) int   i4;

// Fused attention: per block = one (b,h) and one 64-row Q tile.
// Streams over K in 64-wide tiles: S = QK^T/8 (fp32, register-tiled 4x4),
// mask -> -1e9, + bias, write scores to attn out, online softmax, P.V accum.
__global__ __launch_bounds__(256) void fused_attn_kernel(
    const float* __restrict__ qp, const float* __restrict__ kp,
    const float* __restrict__ vp, const int* __restrict__ maskp,
    const float* __restrict__ biasp, float* __restrict__ outp,
    float* __restrict__ attnp)
{
    // +4 pad keeps 16B alignment for f4 accesses and breaks power-of-2 bank strides
    __shared__ float qsT[HDIM][QT + 4];   // [d][row]
    __shared__ float ksT[HDIM][KT + 4];   // [d][col]
    __shared__ float vs [KT  ][HDIM + 4]; // [k][d]
    __shared__ float ps [QT  ][KT + 4];   // [row][k]

    const int t  = threadIdx.x;
    const int bh = blockIdx.y;
    const int b  = bh >> 4;              // / NHEAD
    const int q0 = blockIdx.x * QT;

    const int cg = t & 15;               // col group 0..15
    const int rg = t >> 4;               // row group 0..15
    const int r0 = rg << 2;              // owns rows r0..r0+3
    const int c0 = cg << 2;              // owns cols c0..c0+3

    const float* qg    = qp    + ((size_t)bh * SEQ + q0) * HDIM;
    const float* kg    = kp    + (size_t)bh * SEQ * HDIM;
    const float* vg    = vp    + (size_t)bh * SEQ * HDIM;
    const float* biasg = biasp + ((size_t)bh * SEQ + q0) * SEQ;
    const int*   maskg = maskp + ((size_t)b  * SEQ + q0) * SEQ;
    float*       attng = attnp + ((size_t)bh * SEQ + q0) * SEQ;
    float*       outg  = outp  + ((size_t)bh * SEQ + q0) * HDIM;

    // ---- load Q tile (transposed into LDS) ----
    #pragma unroll
    for (int it = 0; it < 4; ++it) {
        int i   = t + it * 256;          // f4 index into 64x64 tile
        int row = i >> 4;
        int d0  = (i & 15) << 2;
        f4 val = *reinterpret_cast<const f4*>(qg + row * HDIM + d0);
        qsT[d0 + 0][row] = val[0];
        qsT[d0 + 1][row] = val[1];
        qsT[d0 + 2][row] = val[2];
        qsT[d0 + 3][row] = val[3];
    }

    float m_i[4], l_i[4];
    f4 o[4];
    #pragma unroll
    for (int i = 0; i < 4; ++i) { m_i[i] = -INFINITY; l_i[i] = 0.f; o[i] = (f4)0.f; }

    for (int kt = 0; kt < SEQ / KT; ++kt) {
        const int k0 = kt * KT;
        __syncthreads();   // prev PV done before overwriting ksT/vs/ps

        // ---- load K (transposed) and V (natural) tiles ----
        #pragma unroll
        for (int it = 0; it < 4; ++it) {
            int i   = t + it * 256;
            int row = i >> 4;
            int d0  = (i & 15) << 2;
            f4 kv = *reinterpret_cast<const f4*>(kg + (size_t)(k0 + row) * HDIM + d0);
            ksT[d0 + 0][row] = kv[0];
            ksT[d0 + 1][row] = kv[1];
            ksT[d0 + 2][row] = kv[2];
            ksT[d0 + 3][row] = kv[3];
            f4 vv = *reinterpret_cast<const f4*>(vg + (size_t)(k0 + row) * HDIM + d0);
            *reinterpret_cast<f4*>(&vs[row][d0]) = vv;
        }
        __syncthreads();   // tiles ready

        // ---- S = Q.K^T, 4x4 per thread ----
        f4 sacc[4];
        #pragma unroll
        for (int i = 0; i < 4; ++i) sacc[i] = (f4)0.f;
        #pragma unroll 8
        for (int d = 0; d < HDIM; ++d) {
            f4 qv = *reinterpret_cast<const f4*>(&qsT[d][r0]);
            f4 kv = *reinterpret_cast<const f4*>(&ksT[d][c0]);
            #pragma unroll
            for (int i = 0; i < 4; ++i)
                sacc[i] += qv[i] * kv;
        }

        // ---- mask, bias, write scores to attn output ----
        f4 srow[4];
        #pragma unroll
        for (int i = 0; i < 4; ++i) {
            size_t rowoff = (size_t)(r0 + i) * SEQ + k0 + c0;
            i4 mv = *reinterpret_cast<const i4*>(maskg + rowoff);
            f4 bv = *reinterpret_cast<const f4*>(biasg + rowoff);
            f4 sc = sacc[i] * 0.125f;
            #pragma unroll
            for (int j = 0; j < 4; ++j)
                sc[j] = (mv[j] == 0 ? -1e9f : sc[j]) + bv[j];
            srow[i] = sc;
            *reinterpret_cast<f4*>(attng + rowoff) = sc;
        }

        // ---- online softmax update (row spread across 16 lanes) ----
        #pragma unroll
        for (int i = 0; i < 4; ++i) {
            float mx = fmaxf(fmaxf(srow[i][0], srow[i][1]),
                             fmaxf(srow[i][2], srow[i][3]));
            #pragma unroll
            for (int off = 1; off < 16; off <<= 1)
                mx = fmaxf(mx, __shfl_xor(mx, off));
            float mnew = fmaxf(m_i[i], mx);
            float corr = __expf(m_i[i] - mnew);
            f4 p;
            float rsum = 0.f;
            #pragma unroll
            for (int j = 0; j < 4; ++j) { p[j] = __expf(srow[i][j] - mnew); rsum += p[j]; }
            #pragma unroll
            for (int off = 1; off < 16; off <<= 1)
                rsum += __shfl_xor(rsum, off);
            l_i[i] = l_i[i] * corr + rsum;
            m_i[i] = mnew;
            o[i]  *= corr;
            *reinterpret_cast<f4*>(&ps[r0 + i][c0]) = p;
        }
        __syncthreads();   // ps ready

        // ---- O += P.V, 4x4 per thread ----
        #pragma unroll 4
        for (int kk = 0; kk < KT; kk += 4) {
            f4 pr[4];
            #pragma unroll
            for (int i = 0; i < 4; ++i)
                pr[i] = *reinterpret_cast<const f4*>(&ps[r0 + i][kk]);
            #pragma unroll
            for (int u = 0; u < 4; ++u) {
                f4 vv = *reinterpret_cast<const f4*>(&vs[kk + u][c0]);
                #pragma unroll
                for (int i = 0; i < 4; ++i)
                    o[i] += pr[i][u] * vv;
            }
        }
    }

    // ---- epilogue: O / l ----
    #pragma unroll
    for (int i = 0; i < 4; ++i) {
        f4 res = o[i] * (1.f / l_i[i]);
        *reinterpret_cast<f4*>(outg + (size_t)(r0 + i) * HDIM + c0) = res;
    }
}

extern "C" void kernel_launch(void* const* d_in, const int* in_sizes, int n_in,
                              void* d_out, int out_size, void* d_ws, size_t ws_size,
                              hipStream_t stream) {
    const float* q    = (const float*)d_in[0];
    const float* k    = (const float*)d_in[1];
    const float* v    = (const float*)d_in[2];
    const int*   mask = (const int*)  d_in[3];
    const float* bias = (const float*)d_in[4];
    float* out  = (float*)d_out;
    float* attn = out + (size_t)NBATCH * NHEAD * SEQ * HDIM;  // outputs concat: (output, attn)

    dim3 grid(SEQ / QT, NBATCH * NHEAD);
    fused_attn_kernel<<<grid, dim3(256), 0, stream>>>(q, k, v, mask, bias, out, attn);
}

// Round 2
// 835.703 us; speedup vs baseline: 1.5126x; 1.5126x over previous
//
#include <hip/hip_runtime.h>
#include <math.h>

#define NBATCH 4
#define NHEAD  16
#define SEQ    2048
#define HDIM   64
#define QT     64
#define KT     64
#define NTILE  (SEQ / KT)

typedef __attribute__((ext_vector_type(4))) float f4;
typedef __attribute__((ext_vector_type(4))) int   i4;
typedef __attribute__((ext_vector_type(8))) short bf8;   // 8 x bf16
typedef __attribute__((ext_vector_type(4))) short s4;    // 4 x bf16

// round-to-nearest-even f32 -> bf16 (inputs are finite random normals; NaN path not needed)
static __device__ __forceinline__ short f2bf(float f) {
    union { float f; unsigned u; } x; x.f = f;
    unsigned r = x.u + 0x7fffu + ((x.u >> 16) & 1u);
    return (short)(r >> 16);
}

// Block = 256 threads (4 waves), one (b,h) x 64-row Q tile.
// QK^T on MFMA (bf16 in, fp32 acc); softmax + PV on fp32 VALU.
// s_tile rows are wave-private (wave w owns rows 16w..16w+15) -> S-frag scatter,
// softmax read, P in-place write, and PV read all need no extra barrier.
__global__ __launch_bounds__(256) void fused_attn_mfma(
    const float* __restrict__ qp, const float* __restrict__ kp,
    const float* __restrict__ vp, const int* __restrict__ maskp,
    const float* __restrict__ biasp, float* __restrict__ outp,
    float* __restrict__ attnp)
{
    __shared__ float s_tile[QT][KT + 4];   // S (fp32), then P in-place. stride 272B
    __shared__ short ks[KT][HDIM + 8];     // K tile bf16, stride 144B (16B-aligned rows)
    __shared__ float vs[KT][HDIM];         // V tile fp32 (reads are broadcast -> no pad)

    const int t    = threadIdx.x;
    const int w    = t >> 6;               // wave 0..3
    const int lane = t & 63;
    const int g    = lane >> 4;            // 0..3
    const int r    = lane & 15;

    const int bh = blockIdx.y;
    const int b  = bh >> 4;                // / NHEAD
    const int q0 = blockIdx.x * QT;

    const int r0 = (t >> 4) << 2;          // = 16w + 4g : this thread's 4 rows
    const int c0 = (t & 15) << 2;          // this thread's 4 cols (keys / d)

    const float* qg    = qp    + ((size_t)bh * SEQ + q0) * HDIM;
    const float* kg    = kp    + (size_t)bh * SEQ * HDIM;
    const float* vg    = vp    + (size_t)bh * SEQ * HDIM;
    const float* biasg = biasp + ((size_t)bh * SEQ + q0) * SEQ;
    const int*   maskg = maskp + ((size_t)b  * SEQ + q0) * SEQ;
    float*       attng = attnp + ((size_t)bh * SEQ + q0) * SEQ;
    float*       outg  = outp  + ((size_t)bh * SEQ + q0) * HDIM;

    // ---- Q A-fragments, pre-scaled by 1/TEMPERATURE (exact power of 2 in bf16) ----
    // A layout (16x16x32): row = lane&15, k = (lane>>4)*8 + j ; kstep s covers k = 32s..32s+31
    bf8 qfrag[2];
    {
        const int qrow = (w << 4) | r;
        #pragma unroll
        for (int s = 0; s < 2; ++s) {
            const float* p8 = qg + qrow * HDIM + (s << 5) + (g << 3);
            f4 lo = *reinterpret_cast<const f4*>(p8);
            f4 hi = *reinterpret_cast<const f4*>(p8 + 4);
            #pragma unroll
            for (int j = 0; j < 4; ++j) {
                qfrag[s][j]     = f2bf(0.125f * lo[j]);
                qfrag[s][j + 4] = f2bf(0.125f * hi[j]);
            }
        }
    }

    float m_i[4], l_i[4];
    f4 o[4];
    #pragma unroll
    for (int i = 0; i < 4; ++i) {
        m_i[i] = -INFINITY; l_i[i] = 0.f;
        o[i] = (f4){0.f, 0.f, 0.f, 0.f};
    }

    for (int kt = 0; kt < NTILE; ++kt) {
        const int k0 = kt * KT;
        __syncthreads();   // prev tile's PV / frag reads done before restaging ks/vs

        // prefetch mask/bias for this tile: latency hides under staging + barrier drain
        i4 mv[4]; f4 bv[4];
        #pragma unroll
        for (int i = 0; i < 4; ++i) {
            size_t rowoff = (size_t)(r0 + i) * SEQ + k0 + c0;
            mv[i] = *reinterpret_cast<const i4*>(maskg + rowoff);
            bv[i] = *reinterpret_cast<const f4*>(biasg + rowoff);
        }

        // ---- stage K (bf16) and V (f32) tiles, coalesced 256B rows ----
        #pragma unroll
        for (int it = 0; it < 4; ++it) {
            int i   = t + (it << 8);
            int row = i >> 4;
            int c4  = (i & 15) << 2;
            f4 kv = *reinterpret_cast<const f4*>(kg + (size_t)(k0 + row) * HDIM + c4);
            s4 kb = { f2bf(kv[0]), f2bf(kv[1]), f2bf(kv[2]), f2bf(kv[3]) };
            *reinterpret_cast<s4*>(&ks[row][c4]) = kb;
            f4 vv = *reinterpret_cast<const f4*>(vg + (size_t)(k0 + row) * HDIM + c4);
            *reinterpret_cast<f4*>(&vs[row][c4]) = vv;
        }
        __syncthreads();   // ks/vs visible to all waves

        // ---- S = (Q/8) K^T via MFMA: 4 col-tiles x 2 k-steps ----
        // B layout: col = lane&15 (key), k = (lane>>4)*8 + j -> ks[16tc + r][32s + 8g ..]
        f4 acc[4];
        #pragma unroll
        for (int tc = 0; tc < 4; ++tc) acc[tc] = (f4){0.f, 0.f, 0.f, 0.f};
        #pragma unroll
        for (int tc = 0; tc < 4; ++tc) {
            #pragma unroll
            for (int s = 0; s < 2; ++s) {
                bf8 kf = *reinterpret_cast<const bf8*>(&ks[(tc << 4) | r][(s << 5) | (g << 3)]);
                acc[tc] = __builtin_amdgcn_mfma_f32_16x16x32_bf16(qfrag[s], kf, acc[tc], 0, 0, 0);
            }
        }
        // scatter S-frags: D row = (lane>>4)*4 + j (+16w), col = lane&15 (+16tc)
        #pragma unroll
        for (int tc = 0; tc < 4; ++tc) {
            #pragma unroll
            for (int j = 0; j < 4; ++j)
                s_tile[(w << 4) | (g << 2) | j][(tc << 4) | r] = acc[tc][j];
        }

        // ---- mask, bias, attn write, online softmax (4 rows x 4 cols / thread) ----
        #pragma unroll
        for (int i = 0; i < 4; ++i) {
            size_t rowoff = (size_t)(r0 + i) * SEQ + k0 + c0;
            f4 sv = *reinterpret_cast<const f4*>(&s_tile[r0 + i][c0]);
            f4 sc;
            #pragma unroll
            for (int j = 0; j < 4; ++j)
                sc[j] = (mv[i][j] == 0 ? -1e9f : sv[j]) + bv[i][j];
            *reinterpret_cast<f4*>(attng + rowoff) = sc;

            float mx = fmaxf(fmaxf(sc[0], sc[1]), fmaxf(sc[2], sc[3]));
            #pragma unroll
            for (int off = 1; off < 16; off <<= 1)
                mx = fmaxf(mx, __shfl_xor(mx, off));
            float mnew = fmaxf(m_i[i], mx);
            float corr = __expf(m_i[i] - mnew);
            f4 p; float rsum = 0.f;
            #pragma unroll
            for (int j = 0; j < 4; ++j) { p[j] = __expf(sc[j] - mnew); rsum += p[j]; }
            #pragma unroll
            for (int off = 1; off < 16; off <<= 1)
                rsum += __shfl_xor(rsum, off);
            l_i[i] = l_i[i] * corr + rsum;
            m_i[i] = mnew;
            o[i] *= corr;
            *reinterpret_cast<f4*>(&s_tile[r0 + i][c0]) = p;   // P in-place (own cells)
        }

        // ---- O += P V (fp32 VALU; V reads amortized over 4 rows) ----
        #pragma unroll 4
        for (int kk = 0; kk < KT; kk += 4) {
            f4 pr[4];
            #pragma unroll
            for (int i = 0; i < 4; ++i)
                pr[i] = *reinterpret_cast<const f4*>(&s_tile[r0 + i][kk]);
            #pragma unroll
            for (int u = 0; u < 4; ++u) {
                f4 vv = *reinterpret_cast<const f4*>(&vs[kk + u][c0]);
                #pragma unroll
                for (int i = 0; i < 4; ++i)
                    o[i] += pr[i][u] * vv;
            }
        }
    }

    // ---- epilogue: O / l ----
    #pragma unroll
    for (int i = 0; i < 4; ++i) {
        f4 res = o[i] * (1.f / l_i[i]);
        *reinterpret_cast<f4*>(outg + (size_t)(r0 + i) * HDIM + c0) = res;
    }
}

extern "C" void kernel_launch(void* const* d_in, const int* in_sizes, int n_in,
                              void* d_out, int out_size, void* d_ws, size_t ws_size,
                              hipStream_t stream) {
    const float* q    = (const float*)d_in[0];
    const float* k    = (const float*)d_in[1];
    const float* v    = (const float*)d_in[2];
    const int*   mask = (const int*)  d_in[3];
    const float* bias = (const float*)d_in[4];
    float* out  = (float*)d_out;
    float* attn = out + (size_t)NBATCH * NHEAD * SEQ * HDIM;  // outputs concat: (output, attn)

    dim3 grid(SEQ / QT, NBATCH * NHEAD);
    fused_attn_mfma<<<grid, dim3(256), 0, stream>>>(q, k, v, mask, bias, out, attn);
}